// Round 9
// baseline (291.906 us; speedup 1.0000x reference)
//
#include <hip/hip_runtime.h>
#include <hip/hip_bf16.h>

#define NH 16
#define HD 64
#define EMB 1024
#define BB 4
#define TT 2048
#define MTOT (BB*TT)        // 8192 rows
#define N1 (3*NH*HD)        // 3072
#define KD EMB              // 1024

#define BM 128
#define BN 128
#define BK 32

// q scale: (1/sqrt(HD)) * log2(e) — softmax computed in exp2 domain
#define QSCALE 0.18033688011112042f

typedef __bf16 bf16x8 __attribute__((ext_vector_type(8)));
typedef __bf16 bf16x4 __attribute__((ext_vector_type(4)));
typedef float  f32x4  __attribute__((ext_vector_type(4)));
typedef __hip_bfloat16 hbf;

__device__ __forceinline__ void async_copy16(const hbf* g, hbf* l) {
    __builtin_amdgcn_global_load_lds(
        (const __attribute__((address_space(1))) void*)g,
        (__attribute__((address_space(3))) void*)l, 16, 0, 0);
}

__device__ __forceinline__ bf16x4 pack4(float x0, float x1, float x2, float x3) {
    union { bf16x4 v; __hip_bfloat162 h[2]; } u;
    u.h[0] = __float22bfloat162_rn(float2{x0, x1});
    u.h[1] = __float22bfloat162_rn(float2{x2, x3});
    return u.v;
}

// ---------------- conversion kernels ----------------

__global__ __launch_bounds__(256) void f32_to_bf16_v4(const float* __restrict__ in,
                                                      hbf* __restrict__ out, int n4) {
    int i = blockIdx.x * blockDim.x + threadIdx.x;
    if (i < n4) {
        float4 v = ((const float4*)in)[i];
        *(bf16x4*)(out + 4 * (size_t)i) = pack4(v.x, v.y, v.z, v.w);
    }
}

// LDS-tiled transposing convert: out[c*R + r] = bf16(in[r*C + c]); R,C % 64 == 0
__global__ __launch_bounds__(256) void f32_to_bf16_T(const float* __restrict__ in,
                                                     hbf* __restrict__ out, int R, int C) {
    __shared__ float T[64][65];
    int bc = blockIdx.x % (C / 64), br = blockIdx.x / (C / 64);
    int r0 = br * 64, c0 = bc * 64;
    int tr = threadIdx.x >> 6, tc = threadIdx.x & 63;
    #pragma unroll
    for (int i = 0; i < 16; ++i)
        T[4 * i + tr][tc] = in[(size_t)(r0 + 4 * i + tr) * C + c0 + tc];
    __syncthreads();
    #pragma unroll
    for (int i = 0; i < 16; ++i)
        out[(size_t)(c0 + 4 * i + tr) * R + r0 + tc] = __float2bfloat16(T[tc][4 * i + tr]);
}

// ---------------- tiled GEMM core (m97 structure) ----------------

#define GEMM_STAGE(Sdst, Gsrc, ld)                                            \
    {                                                                         \
        _Pragma("unroll")                                                     \
        for (int q = 0; q < 2; ++q) {                                         \
            int e = q * 2048 + tid * 8;                                       \
            int row = e >> 5, col = e & 31;                                   \
            async_copy16(Gsrc + (size_t)row * (ld) + col,                     \
                         Sdst + q * 2048 + (tid & ~63) * 8);                  \
        }                                                                     \
    }

__global__ __launch_bounds__(256) void gemm_qkv(
    const hbf* __restrict__ A, const hbf* __restrict__ Bt,
    hbf* __restrict__ qh, hbf* __restrict__ kh, hbf* __restrict__ vt)
{
    __shared__ __align__(16) hbf As[BM * BK];
    __shared__ __align__(16) hbf Bs[BN * BK];
    int tid = threadIdx.x;
    int wv = tid >> 6, lane = tid & 63;
    int g = lane >> 4, c = lane & 15;
    int wr = wv >> 1, wc = wv & 1;
    int bn = blockIdx.x % (N1 / BN);
    int bm = blockIdx.x / (N1 / BN);
    int m0 = bm * BM, n0 = bn * BN;

    f32x4 acc[4][4];
    #pragma unroll
    for (int i = 0; i < 4; ++i)
        #pragma unroll
        for (int j = 0; j < 4; ++j) acc[i][j] = (f32x4){0.f, 0.f, 0.f, 0.f};

    for (int k0 = 0; k0 < KD; k0 += BK) {
        const hbf* Ag = A  + (size_t)m0 * KD + k0;
        const hbf* Bg = Bt + (size_t)n0 * KD + k0;
        GEMM_STAGE(As, Ag, KD);
        GEMM_STAGE(Bs, Bg, KD);
        __syncthreads();
        bf16x8 af[4], bf[4];
        #pragma unroll
        for (int mi = 0; mi < 4; ++mi)
            af[mi] = *(const bf16x8*)(As + (wr * 64 + mi * 16 + c) * BK + g * 8);
        #pragma unroll
        for (int ni = 0; ni < 4; ++ni)
            bf[ni] = *(const bf16x8*)(Bs + (wc * 64 + ni * 16 + c) * BK + g * 8);
        #pragma unroll
        for (int mi = 0; mi < 4; ++mi)
            #pragma unroll
            for (int ni = 0; ni < 4; ++ni)
                acc[mi][ni] = __builtin_amdgcn_mfma_f32_16x16x32_bf16(af[mi], bf[ni], acc[mi][ni], 0, 0, 0);
        __syncthreads();
    }

    int colbase = n0 + wc * 64;
    int which = colbase / (NH * HD);
    int h = (colbase % (NH * HD)) / HD;
    int b = m0 / TT;
    float scale = (which == 0) ? QSCALE : 1.0f;
    if (which < 2) {
        hbf* dst = (which == 0) ? qh : kh;
        dst += ((size_t)b * NH + h) * TT * HD;
        #pragma unroll
        for (int mi = 0; mi < 4; ++mi)
            #pragma unroll
            for (int ni = 0; ni < 4; ++ni) {
                int d = ni * 16 + c;
                #pragma unroll
                for (int r = 0; r < 4; ++r) {
                    int t = (m0 + wr * 64 + mi * 16 + g * 4 + r) % TT;
                    dst[(size_t)t * HD + d] = __float2bfloat16(acc[mi][ni][r] * scale);
                }
            }
    } else {
        hbf* dst = vt + ((size_t)b * NH + h) * TT * HD;   // [HD][TT] per head
        #pragma unroll
        for (int mi = 0; mi < 4; ++mi)
            #pragma unroll
            for (int ni = 0; ni < 4; ++ni) {
                int d = ni * 16 + c;
                #pragma unroll
                for (int r = 0; r < 4; ++r) {
                    int t = (m0 + wr * 64 + mi * 16 + g * 4 + r) % TT;
                    dst[(size_t)d * TT + t] = __float2bfloat16(acc[mi][ni][r]);
                }
            }
    }
}

// ---------------- flash attention v5: 2 waves x 32q, 4 blocks/CU ----------------
// Block = 128 thr = 2 waves; 64-q supertile (wave wv owns q-tiles qb+32wv and
// qb+32wv+16, sharing every K/V fragment read). 128-key LDS stages
// (global_load_lds w16, XOR-swizzled source; staging offsets precomputed).
// S^T = K·Q^T (in-lane softmax, exp2 domain), O^T = V^T·P^T via per-wave P.
// Causal balance: block runs supertile pair (pi, 31-pi) → uniform 17 stages.

__global__ __launch_bounds__(128, 2) void attn(
    const hbf* __restrict__ qh, const hbf* __restrict__ kh, const hbf* __restrict__ vt,
    hbf* __restrict__ y)
{
    __shared__ __align__(16) hbf Ks[128 * 64];      // 16 KB [key][dim-swz]
    __shared__ __align__(16) hbf Vs[2 * 64 * 64];   // 16 KB [ch][dim][key-swz]
    __shared__ __align__(16) hbf Ps[2][2][16 * 64]; //  8 KB per-wave, per-tile P^T

    int tid = threadIdx.x;
    int wv = tid >> 6, lane = tid & 63;
    int g = lane >> 4, c = lane & 15;
    int c7 = c & 7;

    int bh = blockIdx.x >> 4;       // 16 supertile-pairs per (b,h)
    int pi = blockIdx.x & 15;
    int b = bh >> 4, h = bh & 15;

    const hbf* Q = qh + (size_t)bh * TT * HD;
    const hbf* K = kh + (size_t)bh * TT * HD;
    const hbf* V = vt + (size_t)bh * TT * HD;   // [HD][TT]
    hbf* PqA = &Ps[wv][0][0];
    hbf* PqB = &Ps[wv][1][0];

    // staging source offsets (k0-independent, hoisted out of the k-loop)
    int koff[8], voff[8];
    #pragma unroll
    for (int it = 0; it < 8; ++it) {
        int e = it * 1024 + tid * 8;
        int key = e >> 6, sblk = (e >> 3) & 7;
        koff[it] = key * HD + ((sblk ^ (key & 7)) << 3);
        int ch = e >> 12, rem = e & 4095;
        int dim = rem >> 6, kb8 = (rem >> 3) & 7;
        voff[it] = dim * TT + ch * 64 + ((kb8 ^ (dim & 7)) << 3);
    }
    int ldsb = (tid & ~63) * 8;

    #pragma unroll
    for (int pass = 0; pass < 2; ++pass) {
        int sst = pass ? (31 - pi) : pi;
        int qb = sst * 64;
        int qA = qb + wv * 32;
        int qB = qA + 16;
        int kendA = qA + 16, kendB = qA + 32;
        int kmax = qb + 64;

        bf16x8 aqA0 = *(const bf16x8*)(Q + (size_t)(qA + c) * HD + g * 8);
        bf16x8 aqA1 = *(const bf16x8*)(Q + (size_t)(qA + c) * HD + 32 + g * 8);
        bf16x8 aqB0 = *(const bf16x8*)(Q + (size_t)(qB + c) * HD + g * 8);
        bf16x8 aqB1 = *(const bf16x8*)(Q + (size_t)(qB + c) * HD + 32 + g * 8);

        float m_s[2] = {-1e30f, -1e30f}, l_s[2] = {0.f, 0.f};
        f32x4 o[2][4];
        #pragma unroll
        for (int qi = 0; qi < 2; ++qi)
            #pragma unroll
            for (int d = 0; d < 4; ++d) o[qi][d] = (f32x4){0.f, 0.f, 0.f, 0.f};

        for (int k0 = 0; k0 < kmax; k0 += 128) {
            __syncthreads();   // prior stage's LDS reads complete
            #pragma unroll
            for (int it = 0; it < 8; ++it)
                async_copy16(K + (size_t)k0 * HD + koff[it], Ks + it * 1024 + ldsb);
            #pragma unroll
            for (int it = 0; it < 8; ++it)
                async_copy16(V + k0 + voff[it], Vs + it * 1024 + ldsb);
            __syncthreads();   // staged

            #pragma unroll
            for (int ch = 0; ch < 2; ++ch) {
                int c64 = k0 + ch * 64;
                if (c64 < kendB) {                        // wave-uniform
                    // ---- S^T = K·Q^T for both q-tiles (K fragments shared) ----
                    f32x4 s[2][4];
                    #pragma unroll
                    for (int t = 0; t < 4; ++t) {
                        int kt = c64 + 16 * t;
                        if (kt < kendB) {                 // wave-uniform
                            int rb = (ch * 64 + 16 * t + c) * 64;
                            bf16x8 kf0 = *(const bf16x8*)(Ks + rb + ((g ^ c7) << 3));
                            bf16x8 kf1 = *(const bf16x8*)(Ks + rb + (((4 + g) ^ c7) << 3));
                            if (kt < kendA) {
                                f32x4 a = (f32x4){0.f, 0.f, 0.f, 0.f};
                                a = __builtin_amdgcn_mfma_f32_16x16x32_bf16(kf0, aqA0, a, 0, 0, 0);
                                a = __builtin_amdgcn_mfma_f32_16x16x32_bf16(kf1, aqA1, a, 0, 0, 0);
                                if (kt == qA) {           // diagonal: key<=q ⇔ g*4+r<=c
                                    #pragma unroll
                                    for (int r = 0; r < 4; ++r)
                                        a[r] = (g * 4 + r <= c) ? a[r] : -1e30f;
                                }
                                s[0][t] = a;
                            } else
                                s[0][t] = (f32x4){-1e30f, -1e30f, -1e30f, -1e30f};
                            f32x4 a1 = (f32x4){0.f, 0.f, 0.f, 0.f};
                            a1 = __builtin_amdgcn_mfma_f32_16x16x32_bf16(kf0, aqB0, a1, 0, 0, 0);
                            a1 = __builtin_amdgcn_mfma_f32_16x16x32_bf16(kf1, aqB1, a1, 0, 0, 0);
                            if (kt == qB) {
                                #pragma unroll
                                for (int r = 0; r < 4; ++r)
                                    a1[r] = (g * 4 + r <= c) ? a1[r] : -1e30f;
                            }
                            s[1][t] = a1;
                        } else {
                            s[0][t] = (f32x4){-1e30f, -1e30f, -1e30f, -1e30f};
                            s[1][t] = (f32x4){-1e30f, -1e30f, -1e30f, -1e30f};
                        }
                    }
                    // ---- online softmax (exp2 domain) per q-tile ----
                    #pragma unroll
                    for (int qi = 0; qi < 2; ++qi) {
                        int kend = qi ? kendB : kendA;
                        if (c64 < kend) {                 // wave-uniform
                            f32x4 vmax = s[qi][0];
                            #pragma unroll
                            for (int t = 1; t < 4; ++t)
                                #pragma unroll
                                for (int r = 0; r < 4; ++r)
                                    vmax[r] = fmaxf(vmax[r], s[qi][t][r]);
                            float mx = fmaxf(fmaxf(vmax[0], vmax[1]), fmaxf(vmax[2], vmax[3]));
                            mx = fmaxf(mx, __shfl_xor(mx, 16));
                            mx = fmaxf(mx, __shfl_xor(mx, 32));
                            float mn = fmaxf(m_s[qi], mx);
                            float al = exp2f(m_s[qi] - mn);
                            m_s[qi] = mn;
                            f32x4 vsum = (f32x4){0.f, 0.f, 0.f, 0.f};
                            hbf* Pq = qi ? PqB : PqA;
                            #pragma unroll
                            for (int t = 0; t < 4; ++t) {
                                f32x4 e;
                                #pragma unroll
                                for (int r = 0; r < 4; ++r) e[r] = exp2f(s[qi][t][r] - mn);
                                vsum += e;
                                *(bf16x4*)(Pq + c * 64 + (((2 * t + (g >> 1)) ^ c7) << 3) + ((g & 1) << 2)) =
                                    pack4(e[0], e[1], e[2], e[3]);
                            }
                            float sum = vsum[0] + vsum[1] + vsum[2] + vsum[3];
                            sum += __shfl_xor(sum, 16);
                            sum += __shfl_xor(sum, 32);
                            l_s[qi] = l_s[qi] * al + sum;
                            if (__any(al != 1.0f)) {      // skip rescale when m unchanged
                                #pragma unroll
                                for (int d = 0; d < 4; ++d)
                                    #pragma unroll
                                    for (int r = 0; r < 4; ++r) o[qi][d][r] *= al;
                            }
                        }
                    }
                    // ---- O^T += V^T·P^T (V fragments shared across q-tiles) ----
                    #pragma unroll
                    for (int sc = 0; sc < 2; ++sc) {
                        int kc = c64 + 32 * sc;
                        if (kc < kendB) {                 // wave-uniform
                            bool lA = kc < kendA;
                            bf16x8 pfB = *(const bf16x8*)(PqB + c * 64 + (((4 * sc + g) ^ c7) << 3));
                            bf16x8 pfA;
                            if (lA)
                                pfA = *(const bf16x8*)(PqA + c * 64 + (((4 * sc + g) ^ c7) << 3));
                            #pragma unroll
                            for (int d = 0; d < 4; ++d) {
                                int dim = d * 16 + c;
                                bf16x8 vf = *(const bf16x8*)(Vs + ch * 4096 + dim * 64 +
                                                             (((4 * sc + g) ^ c7) << 3));
                                if (lA)
                                    o[0][d] = __builtin_amdgcn_mfma_f32_16x16x32_bf16(vf, pfA, o[0][d], 0, 0, 0);
                                o[1][d] = __builtin_amdgcn_mfma_f32_16x16x32_bf16(vf, pfB, o[1][d], 0, 0, 0);
                            }
                        }
                    }
                }
            }
        }

        // epilogue: O^T lane holds dims d*16+g*4..+3 of q-row q0+c
        #pragma unroll
        for (int qi = 0; qi < 2; ++qi) {
            int q0 = qA + qi * 16;
            float inv = 1.0f / l_s[qi];
            #pragma unroll
            for (int d = 0; d < 4; ++d) {
                *(bf16x4*)(y + (size_t)(b * TT + q0 + c) * EMB + h * HD + d * 16 + g * 4) =
                    pack4(o[qi][d][0] * inv, o[qi][d][1] * inv,
                          o[qi][d][2] * inv, o[qi][d][3] * inv);
            }
        }
    }
}

// ---------------- GEMM 2: out = y @ W_proj + b_proj ----------------

__global__ __launch_bounds__(256) void gemm_out(
    const hbf* __restrict__ A, const hbf* __restrict__ Bt,
    const float* __restrict__ bias, float* __restrict__ out)
{
    __shared__ __align__(16) hbf As[BM * BK];
    __shared__ __align__(16) hbf Bs[BN * BK];
    int tid = threadIdx.x;
    int wv = tid >> 6, lane = tid & 63;
    int g = lane >> 4, c = lane & 15;
    int wr = wv >> 1, wc = wv & 1;
    int bn = blockIdx.x % (EMB / BN);
    int bm = blockIdx.x / (EMB / BN);
    int m0 = bm * BM, n0 = bn * BN;

    f32x4 acc[4][4];
    #pragma unroll
    for (int i = 0; i < 4; ++i)
        #pragma unroll
        for (int j = 0; j < 4; ++j) acc[i][j] = (f32x4){0.f, 0.f, 0.f, 0.f};

    for (int k0 = 0; k0 < EMB; k0 += BK) {
        const hbf* Ag = A  + (size_t)m0 * EMB + k0;
        const hbf* Bg = Bt + (size_t)n0 * EMB + k0;
        GEMM_STAGE(As, Ag, EMB);
        GEMM_STAGE(Bs, Bg, EMB);
        __syncthreads();
        bf16x8 af[4], bf[4];
        #pragma unroll
        for (int mi = 0; mi < 4; ++mi)
            af[mi] = *(const bf16x8*)(As + (wr * 64 + mi * 16 + c) * BK + g * 8);
        #pragma unroll
        for (int ni = 0; ni < 4; ++ni)
            bf[ni] = *(const bf16x8*)(Bs + (wc * 64 + ni * 16 + c) * BK + g * 8);
        #pragma unroll
        for (int mi = 0; mi < 4; ++mi)
            #pragma unroll
            for (int ni = 0; ni < 4; ++ni)
                acc[mi][ni] = __builtin_amdgcn_mfma_f32_16x16x32_bf16(af[mi], bf[ni], acc[mi][ni], 0, 0, 0);
        __syncthreads();
    }

    #pragma unroll
    for (int mi = 0; mi < 4; ++mi)
        #pragma unroll
        for (int ni = 0; ni < 4; ++ni) {
            int col = n0 + wc * 64 + ni * 16 + c;
            float bv = bias[col];
            #pragma unroll
            for (int r = 0; r < 4; ++r) {
                int row = m0 + wr * 64 + mi * 16 + g * 4 + r;
                out[(size_t)row * EMB + col] = acc[mi][ni][r] + bv;
            }
        }
}

// ---------------- launch ----------------

extern "C" void kernel_launch(void* const* d_in, const int* in_sizes, int n_in,
                              void* d_out, int out_size, void* d_ws, size_t ws_size,
                              hipStream_t stream)
{
    const float* x      = (const float*)d_in[0];
    const float* W_attn = (const float*)d_in[1];
    const float* W_proj = (const float*)d_in[2];
    const float* b_proj = (const float*)d_in[3];
    float* out = (float*)d_out;

    char* ws = (char*)d_ws;
    hbf* xb    = (hbf*)ws; ws += (size_t)MTOT * KD * 2;
    hbf* wab_t = (hbf*)ws; ws += (size_t)N1 * KD * 2;
    hbf* wpb_t = (hbf*)ws; ws += (size_t)EMB * EMB * 2;
    hbf* qh    = (hbf*)ws; ws += (size_t)MTOT * EMB * 2;
    hbf* kh    = (hbf*)ws; ws += (size_t)MTOT * EMB * 2;
    hbf* vt    = (hbf*)ws; ws += (size_t)MTOT * EMB * 2;
    hbf* yb    = (hbf*)ws; ws += (size_t)MTOT * EMB * 2;

    f32_to_bf16_v4<<<(MTOT * KD / 4 + 255) / 256, 256, 0, stream>>>(x, xb, MTOT * KD / 4);
    f32_to_bf16_T<<<(KD / 64) * (N1 / 64), 256, 0, stream>>>(W_attn, wab_t, KD, N1);
    f32_to_bf16_T<<<(KD / 64) * (EMB / 64), 256, 0, stream>>>(W_proj, wpb_t, KD, EMB);

    gemm_qkv<<<(MTOT / BM) * (N1 / BN), 256, 0, stream>>>(xb, wab_t, qh, kh, vt);
    attn<<<BB * NH * 16, 128, 0, stream>>>(qh, kh, vt, yb);
    gemm_out<<<(MTOT / BM) * (EMB / BN), 256, 0, stream>>>(yb, wpb_t, b_proj, out);
}